// Round 7
// baseline (8660.561 us; speedup 1.0000x reference)
//
#include <hip/hip_runtime.h>
#include <hip/hip_bf16.h>

#define N_NODES 50000
#define N_EDGES 800000
#define N_GRAPH 500
#define ND 64
#define ED 32
#define HD 128
#define WPB 4   // waves per block (256 threads)

typedef __attribute__((ext_vector_type(8))) short bf16x8;
typedef __attribute__((ext_vector_type(4))) float f32x4;

__device__ __forceinline__ float sp(float x) {
    return fmaxf(x, 0.f) + log1pf(expf(-fabsf(x)));
}

// fast softplus for the bf16 edge path (v_exp_f32/v_log_f32 based)
__device__ __forceinline__ float spf(float x) {
    return fmaxf(x, 0.f) + __logf(1.f + __expf(-fabsf(x)));
}

__device__ __forceinline__ unsigned short f2bf(float v) {
    __hip_bfloat16 b = __float2bfloat16(v);
    return *(unsigned short*)&b;
}

__device__ __forceinline__ unsigned int pkbf(float a, float b) {
    return (unsigned int)f2bf(a) | ((unsigned int)f2bf(b) << 16);
}

// ---------------- node projection + BN (fp32) ---------------------------
__global__ __launch_bounds__(256) void k_node_proj(
    const float* __restrict__ x, const float* __restrict__ Wnp,
    const float* __restrict__ bnp, float* __restrict__ t,
    float* __restrict__ stats) {
    int lane = threadIdx.x & 63;
    int wave = (blockIdx.x * blockDim.x + threadIdx.x) >> 6;
    int nw = (gridDim.x * blockDim.x) >> 6;
    float w[13];
#pragma unroll
    for (int k = 0; k < 13; ++k) w[k] = Wnp[k * ND + lane];
    float bb = bnp[lane];
    float s0 = 0.f, s1 = 0.f;
    for (int i = wave; i < N_NODES; i += nw) {
        float acc = bb;
#pragma unroll
        for (int k = 0; k < 13; ++k) acc += x[i * 13 + k] * w[k];
        float v = sp(acc);
        t[i * ND + lane] = v;
        s0 += v; s1 += v * v;
    }
    atomicAdd(&stats[lane], s0);
    atomicAdd(&stats[ND + lane], s1);
}

__global__ void k_bn_finalize(const float* __restrict__ stats,
                              const float* __restrict__ g,
                              const float* __restrict__ b,
                              float* __restrict__ ss) {
    int j = threadIdx.x;
    if (j >= ND) return;
    float inv_n = 1.f / (float)N_NODES;
    float mu = stats[j] * inv_n;
    float var = stats[ND + j] * inv_n - mu * mu;
    float rs = rsqrtf(var + 1e-5f);
    float sc = rs * g[j];
    ss[j] = sc;
    ss[ND + j] = b[j] - mu * sc;
}

__global__ __launch_bounds__(256) void k_bn_apply(
    const float* __restrict__ t, const float* __restrict__ ss,
    float* __restrict__ h, unsigned short* __restrict__ hb) {
    int idx = blockIdx.x * blockDim.x + threadIdx.x;
    int tot = N_NODES * ND;
    int stride = gridDim.x * blockDim.x;
    for (; idx < tot; idx += stride) {
        int c = idx & (ND - 1);
        float v = t[idx] * ss[c] + ss[ND + c];
        h[idx] = v;
        hb[idx] = f2bf(v);
    }
}

// ---------------- counting sort of edges by dst -------------------------
__global__ __launch_bounds__(256) void k_hist(const int* __restrict__ ei,
                                              int* __restrict__ hist) {
    int e = blockIdx.x * 256 + threadIdx.x;
    if (e < N_EDGES) atomicAdd(&hist[ei[N_EDGES + e]], 1);
}

__global__ __launch_bounds__(1024) void k_scan1(const int* __restrict__ hist,
                                                int* __restrict__ chunksum) {
    __shared__ int s[1024];
    int t = threadIdx.x;
    int i = blockIdx.x * 1024 + t;
    s[t] = (i < N_NODES) ? hist[i] : 0;
    __syncthreads();
    for (int off = 512; off; off >>= 1) {
        if (t < off) s[t] += s[t + off];
        __syncthreads();
    }
    if (t == 0) chunksum[blockIdx.x] = s[0];
}

__global__ void k_scan2(int* __restrict__ chunksum, int n) {
    if (threadIdx.x == 0) {
        int acc = 0;
        for (int i = 0; i < n; ++i) { int v = chunksum[i]; chunksum[i] = acc; acc += v; }
    }
}

__global__ __launch_bounds__(1024) void k_scan3(const int* __restrict__ hist,
                                                const int* __restrict__ chunksum,
                                                int* __restrict__ cursor,
                                                int* __restrict__ rowptr) {
    __shared__ int s[1024];
    int t = threadIdx.x;
    int i = blockIdx.x * 1024 + t;
    int v = (i < N_NODES) ? hist[i] : 0;
    s[t] = v;
    __syncthreads();
    for (int off = 1; off < 1024; off <<= 1) {
        int u = (t >= off) ? s[t - off] : 0;
        __syncthreads();
        s[t] += u;
        __syncthreads();
    }
    if (i < N_NODES) {
        int ex = chunksum[blockIdx.x] + s[t] - v;  // exclusive scan
        cursor[i] = ex;
        rowptr[i] = ex;
    }
}

__global__ __launch_bounds__(256) void k_scatter(const int* __restrict__ ei,
                                                 int* __restrict__ cursor,
                                                 int* __restrict__ sS,
                                                 int* __restrict__ sE) {
    int e = blockIdx.x * 256 + threadIdx.x;
    if (e >= N_EDGES) return;
    int d = ei[N_EDGES + e];
    int pos = atomicAdd(&cursor[d], 1);
    sS[pos] = ei[e];
    sE[pos] = e;
}

// edge projection into sorted order (layer-invariant, once per call)
__global__ __launch_bounds__(256) void k_eproj_sorted(
    const float* __restrict__ ea, const int* __restrict__ sE,
    const float* __restrict__ Wep, const float* __restrict__ bep,
    unsigned short* __restrict__ e_bf) {
    long idx = (long)blockIdx.x * blockDim.x + threadIdx.x;
    long tot = (long)N_EDGES * 32;
    if (idx >= tot) return;
    int p = (int)(idx >> 5), col = (int)(idx & 31);
    int e = sE[p];
    float v = spf(ea[2 * e] * Wep[col] + ea[2 * e + 1] * Wep[32 + col] + bep[col]);
    e_bf[idx] = f2bf(v);
}

// ---------------- weight pack: W[K][128] -> A-frag layout ---------------
__global__ __launch_bounds__(256) void k_pack_w(
    const float* __restrict__ W, unsigned short* __restrict__ out, int ksteps) {
    int tid = blockIdx.x * blockDim.x + threadIdx.x;
    int total = ksteps * 8 * 64;
    if (tid >= total) return;
    int l = tid & 63; int fr = tid >> 6; int nf = fr & 7; int ks = fr >> 3;
    int n = 16 * nf + (l & 15);
    int k0 = 32 * ks + 8 * (l >> 4);
#pragma unroll
    for (int r = 0; r < 8; ++r)
        out[tid * 8 + r] = f2bf(W[(k0 + r) * 128 + n]);
}

// ---------------- node-centric MFMA edge conv (CSR, no atomics) ---------
// One wave per node: iterate ceil(deg/16) 16-edge MFMA tiles, fused
// 2-layer MLP, mask padded lanes, accumulate sp() outputs in registers,
// shfl-reduce over the 16-edge dimension, single dwordx4 stores to aggr.
template <bool EPRE>
__global__ __launch_bounds__(256, 4) void k_edge_node(
    const unsigned short* __restrict__ h_bf, const unsigned short* __restrict__ e_bf,
    const float* __restrict__ ea, const int* __restrict__ sE,
    const float* __restrict__ Wep, const float* __restrict__ bep,
    const int* __restrict__ rowptr, const int* __restrict__ hist,
    const int* __restrict__ sS,
    const unsigned short* __restrict__ pA1, const float* __restrict__ be1,
    const unsigned short* __restrict__ pA2, const float* __restrict__ be2,
    float* __restrict__ aggr) {
    __shared__ unsigned short P[WPB][16][136];

    int lane = threadIdx.x & 63;
    int w = threadIdx.x >> 6;
    int m = lane & 15, g = lane >> 4;
    int node = blockIdx.x * WPB + w;
    if (node >= N_NODES) return;
    int start = rowptr[node];
    int deg = hist[node];

    float rs[8][4];
#pragma unroll
    for (int nf = 0; nf < 8; ++nf)
#pragma unroll
        for (int j = 0; j < 4; ++j) rs[nf][j] = 0.f;

    int nt = (deg + 15) >> 4;
    for (int t = 0; t < nt; ++t) {
        int rem = deg - (t << 4);           // > 0
        int me = min(m, rem - 1);           // clamped edge slot
        int p = start + (t << 4) + me;      // sorted edge position
        int src = sS[p];
        bool valid = (m < rem);

        f32x4 acc[8];
#pragma unroll
        for (int nf = 0; nf < 8; ++nf) acc[nf] = (f32x4){0.f, 0.f, 0.f, 0.f};

        // ---- GEMM1: K = 160 (dst 64 | src 64 | e 32) ----
#pragma unroll
        for (int ks = 0; ks < 5; ++ks) {
            bf16x8 b;
            if (ks < 2) {
                // dst features: uniform per node (broadcast)
                b = *(const bf16x8*)(h_bf + (size_t)node * 64 + ks * 32 + 8 * g);
            } else if (ks < 4) {
                b = *(const bf16x8*)(h_bf + (size_t)src * 64 + (ks - 2) * 32 + 8 * g);
            } else {
                if constexpr (EPRE) {
                    b = *(const bf16x8*)(e_bf + (size_t)p * 32 + 8 * g);
                } else {
                    int eo = sE[p];
                    float a0 = ea[2 * eo], a1 = ea[2 * eo + 1];
                    bf16x8 bt;
#pragma unroll
                    for (int r = 0; r < 8; ++r) {
                        int col = 8 * g + r;
                        bt[r] = (short)f2bf(spf(a0 * Wep[col] + a1 * Wep[32 + col] + bep[col]));
                    }
                    b = bt;
                }
            }
#pragma unroll
            for (int nf = 0; nf < 8; ++nf) {
                bf16x8 a = *(const bf16x8*)(pA1 + ((ks * 8 + nf) * 64 + lane) * 8);
                acc[nf] = __builtin_amdgcn_mfma_f32_16x16x32_bf16(a, b, acc[nf], 0, 0, 0);
            }
        }

        // ---- epilogue 1: bias + softplus -> P (bf16, wave-private) ----
#pragma unroll
        for (int nf = 0; nf < 8; ++nf) {
            f32x4 bb = *(const f32x4*)(be1 + 16 * nf + 4 * g);
            f32x4 c = acc[nf];
            unsigned int u01 = pkbf(spf(c[0] + bb[0]), spf(c[1] + bb[1]));
            unsigned int u23 = pkbf(spf(c[2] + bb[2]), spf(c[3] + bb[3]));
            unsigned int* dst = (unsigned int*)&P[w][m][16 * nf + 4 * g];
            dst[0] = u01; dst[1] = u23;
        }

        f32x4 acc2[8];
#pragma unroll
        for (int nf = 0; nf < 8; ++nf) acc2[nf] = (f32x4){0.f, 0.f, 0.f, 0.f};

        // ---- GEMM2: K = 128, B = P^T from LDS ----
#pragma unroll
        for (int ks = 0; ks < 4; ++ks) {
            bf16x8 b = *(const bf16x8*)&P[w][m][32 * ks + 8 * g];
#pragma unroll
            for (int nf = 0; nf < 8; ++nf) {
                bf16x8 a = *(const bf16x8*)(pA2 + ((ks * 8 + nf) * 64 + lane) * 8);
                acc2[nf] = __builtin_amdgcn_mfma_f32_16x16x32_bf16(a, b, acc2[nf], 0, 0, 0);
            }
        }

        // ---- epilogue 2: bias + softplus, masked accumulate ----
#pragma unroll
        for (int nf = 0; nf < 8; ++nf) {
            f32x4 bb = *(const f32x4*)(be2 + 16 * nf + 4 * g);
            f32x4 c = acc2[nf];
#pragma unroll
            for (int j = 0; j < 4; ++j) {
                float v = spf(c[j] + bb[j]);
                rs[nf][j] += valid ? v : 0.f;
            }
        }
    }

    // ---- reduce over the 16-edge (m) dimension, store once ----
#pragma unroll
    for (int nf = 0; nf < 8; ++nf)
#pragma unroll
        for (int j = 0; j < 4; ++j) {
            float v = rs[nf][j];
            v += __shfl_xor(v, 1);
            v += __shfl_xor(v, 2);
            v += __shfl_xor(v, 4);
            v += __shfl_xor(v, 8);
            rs[nf][j] = v;
        }
    if (m == 0) {
        float* base = aggr + (size_t)node * HD;
#pragma unroll
        for (int nf = 0; nf < 8; ++nf) {
            f32x4 v = { rs[nf][0], rs[nf][1], rs[nf][2], rs[nf][3] };
            *(f32x4*)(base + 16 * nf + 4 * g) = v;
        }
    }
}

// ---------------- node update (fp32, unchanged) -------------------------
__global__ __launch_bounds__(256) void k_node_update(
    const float* __restrict__ h, const float* __restrict__ aggr,
    const float* __restrict__ Wn1, const float* __restrict__ bn1,
    const float* __restrict__ Wn2, const float* __restrict__ bn2,
    float* __restrict__ t, float* __restrict__ stats) {
    __shared__ float zb[WPB][ND + HD];
    __shared__ float pb[WPB][HD];
    int lane = threadIdx.x & 63;
    int wid = threadIdx.x >> 6;
    int wave = (blockIdx.x * blockDim.x + threadIdx.x) >> 6;
    int nw = (gridDim.x * blockDim.x) >> 6;
    int iters = (N_NODES + nw - 1) / nw;
    float s0 = 0.f, s1 = 0.f;
    for (int it = 0; it < iters; ++it) {
        int i = wave + it * nw;
        bool valid = i < N_NODES;
        int ic = valid ? i : N_NODES - 1;
        float hv = h[ic * ND + lane];
        zb[wid][lane] = hv;
        zb[wid][ND + lane] = aggr[ic * HD + lane];
        zb[wid][ND + 64 + lane] = aggr[ic * HD + 64 + lane];
        __syncthreads();
        float h0 = bn1[lane], h1 = bn1[64 + lane];
#pragma unroll 8
        for (int k = 0; k < ND + HD; ++k) {
            float zk = zb[wid][k];
            h0 += zk * Wn1[k * HD + lane];
            h1 += zk * Wn1[k * HD + 64 + lane];
        }
        pb[wid][lane] = sp(h0);
        pb[wid][64 + lane] = sp(h1);
        __syncthreads();
        float o = bn2[lane];
#pragma unroll 8
        for (int k = 0; k < HD; ++k) o += pb[wid][k] * Wn2[k * ND + lane];
        if (valid) {
            float tn = o + hv;
            t[ic * ND + lane] = tn;
            s0 += tn; s1 += tn * tn;
        }
        __syncthreads();
    }
    atomicAdd(&stats[lane], s0);
    atomicAdd(&stats[ND + lane], s1);
}

// ---------------- pooling + readout (unchanged) -------------------------
__global__ __launch_bounds__(256) void k_pool(
    const float* __restrict__ h, const int* __restrict__ batch,
    float* __restrict__ pooled, float* __restrict__ cnt) {
    int lane = threadIdx.x & 63;
    int wave = (blockIdx.x * blockDim.x + threadIdx.x) >> 6;
    int nw = (gridDim.x * blockDim.x) >> 6;
    int chunk = (N_NODES + nw - 1) / nw;
    int s = wave * chunk;
    int epos = min(N_NODES, s + chunk);
    if (s >= N_NODES) return;
    int curg = batch[s];
    float acc = 0.f, c = 0.f;
    for (int i = s; i < epos; ++i) {
        int g = batch[i];
        if (g != curg) {
            atomicAdd(&pooled[curg * ND + lane], acc);
            if (lane == 0) atomicAdd(&cnt[curg], c);
            acc = 0.f; c = 0.f; curg = g;
        }
        acc += h[i * ND + lane];
        c += 1.f;
    }
    atomicAdd(&pooled[curg * ND + lane], acc);
    if (lane == 0) atomicAdd(&cnt[curg], c);
}

__global__ __launch_bounds__(256) void k_readout(
    const float* __restrict__ pooled, const float* __restrict__ cnt,
    const float* __restrict__ Wo1, const float* __restrict__ bo1,
    const float* __restrict__ Wo2, const float* __restrict__ bo2,
    float* __restrict__ out) {
    __shared__ float pbuf[WPB][ND];
    int lane = threadIdx.x & 63;
    int wid = threadIdx.x >> 6;
    int g = blockIdx.x * WPB + wid;
    bool valid = g < N_GRAPH;
    int gc = valid ? g : N_GRAPH - 1;
    float c = fmaxf(cnt[gc], 1.f);
    pbuf[wid][lane] = pooled[gc * ND + lane] / c;
    __syncthreads();
    float h0 = bo1[lane], h1 = bo1[64 + lane];
#pragma unroll 8
    for (int k = 0; k < ND; ++k) {
        float pk = pbuf[wid][k];
        h0 += pk * Wo1[k * HD + lane];
        h1 += pk * Wo1[k * HD + 64 + lane];
    }
    float s = sp(h0) * Wo2[lane] + sp(h1) * Wo2[64 + lane];
#pragma unroll
    for (int off = 32; off; off >>= 1) s += __shfl_down(s, off);
    if (valid && lane == 0) out[g] = s + bo2[0];
}

extern "C" void kernel_launch(void* const* d_in, const int* in_sizes, int n_in,
                              void* d_out, int out_size, void* d_ws, size_t ws_size,
                              hipStream_t stream) {
    const float* x       = (const float*)d_in[0];
    const float* ea      = (const float*)d_in[1];
    const int*   ei      = (const int*)d_in[2];
    const int*   batch   = (const int*)d_in[3];
    const float* Wnp     = (const float*)d_in[4];
    const float* bnp     = (const float*)d_in[5];
    const float* g_np    = (const float*)d_in[6];
    const float* be_np   = (const float*)d_in[7];
    const float* Wep     = (const float*)d_in[8];
    const float* bep     = (const float*)d_in[9];
    const float* We1     = (const float*)d_in[10];
    const float* be1     = (const float*)d_in[11];
    const float* We2     = (const float*)d_in[12];
    const float* be2     = (const float*)d_in[13];
    const float* Wn1     = (const float*)d_in[14];
    const float* bn1     = (const float*)d_in[15];
    const float* Wn2     = (const float*)d_in[16];
    const float* bn2     = (const float*)d_in[17];
    const float* g_bn    = (const float*)d_in[18];
    const float* b_bn    = (const float*)d_in[19];
    const float* Wo1     = (const float*)d_in[20];
    const float* bo1     = (const float*)d_in[21];
    const float* Wo2     = (const float*)d_in[22];
    const float* bo2     = (const float*)d_in[23];

    float* ws = (float*)d_ws;
    size_t off = 0;
    float* h      = ws + off; off += (size_t)N_NODES * ND;
    float* t      = ws + off; off += (size_t)N_NODES * ND;
    float* aggr   = ws + off; off += (size_t)N_NODES * HD;
    float* stats  = ws + off; off += 2 * ND;
    float* ss     = ws + off; off += 2 * ND;
    float* pooled = ws + off; off += N_GRAPH * ND;
    float* cnt    = ws + off; off += 512;
    unsigned short* h_bf = (unsigned short*)(ws + off); off += (size_t)N_NODES * ND / 2;
    unsigned short* pA1  = (unsigned short*)(ws + off); off += 5 * 8 * 64 * 8 / 2;
    unsigned short* pA2  = (unsigned short*)(ws + off); off += 4 * 8 * 64 * 8 / 2;
    int* sS       = (int*)(ws + off); off += N_EDGES;
    int* sE       = (int*)(ws + off); off += N_EDGES;
    int* hist     = (int*)(ws + off); off += N_NODES;
    int* cursor   = (int*)(ws + off); off += N_NODES;
    int* rowptr   = (int*)(ws + off); off += N_NODES;
    int* chunksum = (int*)(ws + off); off += 64;
    size_t base_bytes = off * sizeof(float);
    unsigned short* e_bf = (unsigned short*)(ws + off);
    bool epre = (ws_size >= base_bytes + (size_t)N_EDGES * 32 * 2);

    float* outp = (float*)d_out;

    const int NCH = (N_NODES + 1023) / 1024;  // 49

    // ---- counting sort of edges by dst -> CSR (once per call) ----
    hipMemsetAsync(hist, 0, N_NODES * sizeof(int), stream);
    k_hist<<<(N_EDGES + 255) / 256, 256, 0, stream>>>(ei, hist);
    k_scan1<<<NCH, 1024, 0, stream>>>(hist, chunksum);
    k_scan2<<<1, 64, 0, stream>>>(chunksum, NCH);
    k_scan3<<<NCH, 1024, 0, stream>>>(hist, chunksum, cursor, rowptr);
    k_scatter<<<(N_EDGES + 255) / 256, 256, 0, stream>>>(ei, cursor, sS, sE);
    if (epre)
        k_eproj_sorted<<<(int)(((long)N_EDGES * 32 + 255) / 256), 256, 0, stream>>>(
            ea, sE, Wep, bep, e_bf);

    // ---- node projection + BN ----
    hipMemsetAsync(stats, 0, 2 * ND * sizeof(float), stream);
    k_node_proj<<<512, 256, 0, stream>>>(x, Wnp, bnp, t, stats);
    k_bn_finalize<<<1, 64, 0, stream>>>(stats, g_np, be_np, ss);
    k_bn_apply<<<2048, 256, 0, stream>>>(t, ss, h, h_bf);

    for (int l = 0; l < 3; ++l) {
        k_pack_w<<<(5 * 8 * 64 + 255) / 256, 256, 0, stream>>>(
            We1 + (size_t)l * 160 * HD, pA1, 5);
        k_pack_w<<<(4 * 8 * 64 + 255) / 256, 256, 0, stream>>>(
            We2 + (size_t)l * HD * HD, pA2, 4);

        if (epre)
            k_edge_node<true><<<(N_NODES + WPB - 1) / WPB, 256, 0, stream>>>(
                h_bf, e_bf, ea, sE, Wep, bep, rowptr, hist, sS,
                pA1, be1 + l * HD, pA2, be2 + l * HD, aggr);
        else
            k_edge_node<false><<<(N_NODES + WPB - 1) / WPB, 256, 0, stream>>>(
                h_bf, e_bf, ea, sE, Wep, bep, rowptr, hist, sS,
                pA1, be1 + l * HD, pA2, be2 + l * HD, aggr);

        hipMemsetAsync(stats, 0, 2 * ND * sizeof(float), stream);
        k_node_update<<<512, 256, 0, stream>>>(
            h, aggr,
            Wn1 + (size_t)l * (ND + HD) * HD, bn1 + l * HD,
            Wn2 + (size_t)l * HD * ND, bn2 + l * ND, t, stats);
        k_bn_finalize<<<1, 64, 0, stream>>>(stats, g_bn + l * ND, b_bn + l * ND, ss);
        k_bn_apply<<<2048, 256, 0, stream>>>(t, ss, h, h_bf);
    }

    hipMemsetAsync(pooled, 0, (size_t)(N_GRAPH * ND + 512) * sizeof(float), stream);
    k_pool<<<512, 256, 0, stream>>>(h, batch, pooled, cnt);
    k_readout<<<(N_GRAPH + WPB - 1) / WPB, 256, 0, stream>>>(
        pooled, cnt, Wo1, bo1, Wo2, bo2, outp);
}

// Round 8
// 4766.558 us; speedup vs baseline: 1.8169x; 1.8169x over previous
//
#include <hip/hip_runtime.h>
#include <hip/hip_bf16.h>

#define N_NODES 50000
#define N_EDGES 800000
#define N_GRAPH 500
#define ND 64
#define ED 32
#define HD 128
#define WPB 4   // waves per block (256 threads)

typedef __attribute__((ext_vector_type(8))) short bf16x8;
typedef __attribute__((ext_vector_type(4))) float f32x4;

__device__ __forceinline__ float sp(float x) {
    return fmaxf(x, 0.f) + log1pf(expf(-fabsf(x)));
}

// fast softplus for the bf16 edge path (v_exp_f32/v_log_f32 based)
__device__ __forceinline__ float spf(float x) {
    return fmaxf(x, 0.f) + __logf(1.f + __expf(-fabsf(x)));
}

__device__ __forceinline__ unsigned short f2bf(float v) {
    __hip_bfloat16 b = __float2bfloat16(v);
    return *(unsigned short*)&b;
}

__device__ __forceinline__ unsigned int pkbf(float a, float b) {
    return (unsigned int)f2bf(a) | ((unsigned int)f2bf(b) << 16);
}

// ---------------- node projection + BN (fp32) ---------------------------
__global__ __launch_bounds__(256) void k_node_proj(
    const float* __restrict__ x, const float* __restrict__ Wnp,
    const float* __restrict__ bnp, float* __restrict__ t,
    float* __restrict__ stats) {
    int lane = threadIdx.x & 63;
    int wave = (blockIdx.x * blockDim.x + threadIdx.x) >> 6;
    int nw = (gridDim.x * blockDim.x) >> 6;
    float w[13];
#pragma unroll
    for (int k = 0; k < 13; ++k) w[k] = Wnp[k * ND + lane];
    float bb = bnp[lane];
    float s0 = 0.f, s1 = 0.f;
    for (int i = wave; i < N_NODES; i += nw) {
        float acc = bb;
#pragma unroll
        for (int k = 0; k < 13; ++k) acc += x[i * 13 + k] * w[k];
        float v = sp(acc);
        t[i * ND + lane] = v;
        s0 += v; s1 += v * v;
    }
    atomicAdd(&stats[lane], s0);
    atomicAdd(&stats[ND + lane], s1);
}

__global__ void k_bn_finalize(const float* __restrict__ stats,
                              const float* __restrict__ g,
                              const float* __restrict__ b,
                              float* __restrict__ ss) {
    int j = threadIdx.x;
    if (j >= ND) return;
    float inv_n = 1.f / (float)N_NODES;
    float mu = stats[j] * inv_n;
    float var = stats[ND + j] * inv_n - mu * mu;
    float rs = rsqrtf(var + 1e-5f);
    float sc = rs * g[j];
    ss[j] = sc;
    ss[ND + j] = b[j] - mu * sc;
}

__global__ __launch_bounds__(256) void k_bn_apply(
    const float* __restrict__ t, const float* __restrict__ ss,
    float* __restrict__ h, unsigned short* __restrict__ hb) {
    int idx = blockIdx.x * blockDim.x + threadIdx.x;
    int tot = N_NODES * ND;
    int stride = gridDim.x * blockDim.x;
    for (; idx < tot; idx += stride) {
        int c = idx & (ND - 1);
        float v = t[idx] * ss[c] + ss[ND + c];
        h[idx] = v;
        hb[idx] = f2bf(v);
    }
}

// ---------------- counting sort of edges by dst -------------------------
__global__ __launch_bounds__(256) void k_hist(const int* __restrict__ ei,
                                              int* __restrict__ hist) {
    int e = blockIdx.x * 256 + threadIdx.x;
    if (e < N_EDGES) atomicAdd(&hist[ei[N_EDGES + e]], 1);
}

__global__ __launch_bounds__(1024) void k_scan1(const int* __restrict__ hist,
                                                int* __restrict__ chunksum) {
    __shared__ int s[1024];
    int t = threadIdx.x;
    int i = blockIdx.x * 1024 + t;
    s[t] = (i < N_NODES) ? hist[i] : 0;
    __syncthreads();
    for (int off = 512; off; off >>= 1) {
        if (t < off) s[t] += s[t + off];
        __syncthreads();
    }
    if (t == 0) chunksum[blockIdx.x] = s[0];
}

__global__ void k_scan2(int* __restrict__ chunksum, int n) {
    if (threadIdx.x == 0) {
        int acc = 0;
        for (int i = 0; i < n; ++i) { int v = chunksum[i]; chunksum[i] = acc; acc += v; }
    }
}

__global__ __launch_bounds__(1024) void k_scan3(const int* __restrict__ hist,
                                                const int* __restrict__ chunksum,
                                                int* __restrict__ cursor,
                                                int* __restrict__ rowptr) {
    __shared__ int s[1024];
    int t = threadIdx.x;
    int i = blockIdx.x * 1024 + t;
    int v = (i < N_NODES) ? hist[i] : 0;
    s[t] = v;
    __syncthreads();
    for (int off = 1; off < 1024; off <<= 1) {
        int u = (t >= off) ? s[t - off] : 0;
        __syncthreads();
        s[t] += u;
        __syncthreads();
    }
    if (i < N_NODES) {
        int ex = chunksum[blockIdx.x] + s[t] - v;  // exclusive scan
        cursor[i] = ex;
        rowptr[i] = ex;
    }
}

__global__ __launch_bounds__(256) void k_scatter(const int* __restrict__ ei,
                                                 int* __restrict__ cursor,
                                                 int* __restrict__ sS,
                                                 int* __restrict__ sE) {
    int e = blockIdx.x * 256 + threadIdx.x;
    if (e >= N_EDGES) return;
    int d = ei[N_EDGES + e];
    int pos = atomicAdd(&cursor[d], 1);
    sS[pos] = ei[e];
    sE[pos] = e;
}

// edge projection into sorted order (layer-invariant, once per call)
__global__ __launch_bounds__(256) void k_eproj_sorted(
    const float* __restrict__ ea, const int* __restrict__ sE,
    const float* __restrict__ Wep, const float* __restrict__ bep,
    unsigned short* __restrict__ e_bf) {
    long idx = (long)blockIdx.x * blockDim.x + threadIdx.x;
    long tot = (long)N_EDGES * 32;
    if (idx >= tot) return;
    int p = (int)(idx >> 5), col = (int)(idx & 31);
    int e = sE[p];
    float v = spf(ea[2 * e] * Wep[col] + ea[2 * e + 1] * Wep[32 + col] + bep[col]);
    e_bf[idx] = f2bf(v);
}

// ---------------- weight pack: W[K][128] -> A-frag layout ---------------
__global__ __launch_bounds__(256) void k_pack_w(
    const float* __restrict__ W, unsigned short* __restrict__ out, int ksteps) {
    int tid = blockIdx.x * blockDim.x + threadIdx.x;
    int total = ksteps * 8 * 64;
    if (tid >= total) return;
    int l = tid & 63; int fr = tid >> 6; int nf = fr & 7; int ks = fr >> 3;
    int n = 16 * nf + (l & 15);
    int k0 = 32 * ks + 8 * (l >> 4);
#pragma unroll
    for (int r = 0; r < 8; ++r)
        out[tid * 8 + r] = f2bf(W[(k0 + r) * 128 + n]);
}

// ---------------- node-centric MFMA edge conv (CSR, no atomics) ---------
// One wave per node. min-waves/EU = 2 -> 256-reg budget: acc/acc2 live in
// AGPRs, rs + temps in VGPRs, NO scratch spill (the round-7 regression was
// the (256,4) 128-reg cap forcing ~7.5 GB of spill traffic).
template <bool EPRE>
__global__ __launch_bounds__(256, 2) void k_edge_node(
    const unsigned short* __restrict__ h_bf, const unsigned short* __restrict__ e_bf,
    const float* __restrict__ ea, const int* __restrict__ sE,
    const float* __restrict__ Wep, const float* __restrict__ bep,
    const int* __restrict__ rowptr, const int* __restrict__ hist,
    const int* __restrict__ sS,
    const unsigned short* __restrict__ pA1, const float* __restrict__ be1,
    const unsigned short* __restrict__ pA2, const float* __restrict__ be2,
    float* __restrict__ aggr) {
    __shared__ unsigned short P[WPB][16][136];

    int lane = threadIdx.x & 63;
    int w = threadIdx.x >> 6;
    int m = lane & 15, g = lane >> 4;
    int node = blockIdx.x * WPB + w;
    if (node >= N_NODES) return;
    int start = rowptr[node];
    int deg = hist[node];

    float rs[8][4];
#pragma unroll
    for (int nf = 0; nf < 8; ++nf)
#pragma unroll
        for (int j = 0; j < 4; ++j) rs[nf][j] = 0.f;

    int nt = (deg + 15) >> 4;
    for (int t = 0; t < nt; ++t) {
        int rem = deg - (t << 4);           // > 0
        int me = min(m, rem - 1);           // clamped edge slot
        int p = start + (t << 4) + me;      // sorted edge position
        int src = sS[p];
        bool valid = (m < rem);

        f32x4 acc[8];
#pragma unroll
        for (int nf = 0; nf < 8; ++nf) acc[nf] = (f32x4){0.f, 0.f, 0.f, 0.f};

        // ---- GEMM1: K = 160 (dst 64 | src 64 | e 32) ----
#pragma unroll
        for (int ks = 0; ks < 5; ++ks) {
            bf16x8 b;
            if (ks < 2) {
                // dst features: uniform per node (broadcast)
                b = *(const bf16x8*)(h_bf + (size_t)node * 64 + ks * 32 + 8 * g);
            } else if (ks < 4) {
                b = *(const bf16x8*)(h_bf + (size_t)src * 64 + (ks - 2) * 32 + 8 * g);
            } else {
                if constexpr (EPRE) {
                    b = *(const bf16x8*)(e_bf + (size_t)p * 32 + 8 * g);
                } else {
                    int eo = sE[p];
                    float a0 = ea[2 * eo], a1 = ea[2 * eo + 1];
                    bf16x8 bt;
#pragma unroll
                    for (int r = 0; r < 8; ++r) {
                        int col = 8 * g + r;
                        bt[r] = (short)f2bf(spf(a0 * Wep[col] + a1 * Wep[32 + col] + bep[col]));
                    }
                    b = bt;
                }
            }
#pragma unroll
            for (int nf = 0; nf < 8; ++nf) {
                bf16x8 a = *(const bf16x8*)(pA1 + ((ks * 8 + nf) * 64 + lane) * 8);
                acc[nf] = __builtin_amdgcn_mfma_f32_16x16x32_bf16(a, b, acc[nf], 0, 0, 0);
            }
        }

        // ---- epilogue 1: bias + softplus -> P (bf16, wave-private) ----
#pragma unroll
        for (int nf = 0; nf < 8; ++nf) {
            f32x4 bb = *(const f32x4*)(be1 + 16 * nf + 4 * g);
            f32x4 c = acc[nf];
            unsigned int u01 = pkbf(spf(c[0] + bb[0]), spf(c[1] + bb[1]));
            unsigned int u23 = pkbf(spf(c[2] + bb[2]), spf(c[3] + bb[3]));
            unsigned int* dst = (unsigned int*)&P[w][m][16 * nf + 4 * g];
            dst[0] = u01; dst[1] = u23;
        }

        f32x4 acc2[8];
#pragma unroll
        for (int nf = 0; nf < 8; ++nf) acc2[nf] = (f32x4){0.f, 0.f, 0.f, 0.f};

        // ---- GEMM2: K = 128, B = P^T from LDS ----
#pragma unroll
        for (int ks = 0; ks < 4; ++ks) {
            bf16x8 b = *(const bf16x8*)&P[w][m][32 * ks + 8 * g];
#pragma unroll
            for (int nf = 0; nf < 8; ++nf) {
                bf16x8 a = *(const bf16x8*)(pA2 + ((ks * 8 + nf) * 64 + lane) * 8);
                acc2[nf] = __builtin_amdgcn_mfma_f32_16x16x32_bf16(a, b, acc2[nf], 0, 0, 0);
            }
        }

        // ---- epilogue 2: bias + softplus, masked accumulate ----
#pragma unroll
        for (int nf = 0; nf < 8; ++nf) {
            f32x4 bb = *(const f32x4*)(be2 + 16 * nf + 4 * g);
            f32x4 c = acc2[nf];
#pragma unroll
            for (int j = 0; j < 4; ++j) {
                float v = spf(c[j] + bb[j]);
                rs[nf][j] += valid ? v : 0.f;
            }
        }
    }

    // ---- reduce over the 16-edge (m) dimension, store once ----
#pragma unroll
    for (int nf = 0; nf < 8; ++nf)
#pragma unroll
        for (int j = 0; j < 4; ++j) {
            float v = rs[nf][j];
            v += __shfl_xor(v, 1);
            v += __shfl_xor(v, 2);
            v += __shfl_xor(v, 4);
            v += __shfl_xor(v, 8);
            rs[nf][j] = v;
        }
    if (m == 0) {
        float* base = aggr + (size_t)node * HD;
#pragma unroll
        for (int nf = 0; nf < 8; ++nf) {
            f32x4 v = { rs[nf][0], rs[nf][1], rs[nf][2], rs[nf][3] };
            *(f32x4*)(base + 16 * nf + 4 * g) = v;
        }
    }
}

// ---------------- node update (fp32, unchanged) -------------------------
__global__ __launch_bounds__(256) void k_node_update(
    const float* __restrict__ h, const float* __restrict__ aggr,
    const float* __restrict__ Wn1, const float* __restrict__ bn1,
    const float* __restrict__ Wn2, const float* __restrict__ bn2,
    float* __restrict__ t, float* __restrict__ stats) {
    __shared__ float zb[WPB][ND + HD];
    __shared__ float pb[WPB][HD];
    int lane = threadIdx.x & 63;
    int wid = threadIdx.x >> 6;
    int wave = (blockIdx.x * blockDim.x + threadIdx.x) >> 6;
    int nw = (gridDim.x * blockDim.x) >> 6;
    int iters = (N_NODES + nw - 1) / nw;
    float s0 = 0.f, s1 = 0.f;
    for (int it = 0; it < iters; ++it) {
        int i = wave + it * nw;
        bool valid = i < N_NODES;
        int ic = valid ? i : N_NODES - 1;
        float hv = h[ic * ND + lane];
        zb[wid][lane] = hv;
        zb[wid][ND + lane] = aggr[ic * HD + lane];
        zb[wid][ND + 64 + lane] = aggr[ic * HD + 64 + lane];
        __syncthreads();
        float h0 = bn1[lane], h1 = bn1[64 + lane];
#pragma unroll 8
        for (int k = 0; k < ND + HD; ++k) {
            float zk = zb[wid][k];
            h0 += zk * Wn1[k * HD + lane];
            h1 += zk * Wn1[k * HD + 64 + lane];
        }
        pb[wid][lane] = sp(h0);
        pb[wid][64 + lane] = sp(h1);
        __syncthreads();
        float o = bn2[lane];
#pragma unroll 8
        for (int k = 0; k < HD; ++k) o += pb[wid][k] * Wn2[k * ND + lane];
        if (valid) {
            float tn = o + hv;
            t[ic * ND + lane] = tn;
            s0 += tn; s1 += tn * tn;
        }
        __syncthreads();
    }
    atomicAdd(&stats[lane], s0);
    atomicAdd(&stats[ND + lane], s1);
}

// ---------------- pooling + readout (unchanged) -------------------------
__global__ __launch_bounds__(256) void k_pool(
    const float* __restrict__ h, const int* __restrict__ batch,
    float* __restrict__ pooled, float* __restrict__ cnt) {
    int lane = threadIdx.x & 63;
    int wave = (blockIdx.x * blockDim.x + threadIdx.x) >> 6;
    int nw = (gridDim.x * blockDim.x) >> 6;
    int chunk = (N_NODES + nw - 1) / nw;
    int s = wave * chunk;
    int epos = min(N_NODES, s + chunk);
    if (s >= N_NODES) return;
    int curg = batch[s];
    float acc = 0.f, c = 0.f;
    for (int i = s; i < epos; ++i) {
        int g = batch[i];
        if (g != curg) {
            atomicAdd(&pooled[curg * ND + lane], acc);
            if (lane == 0) atomicAdd(&cnt[curg], c);
            acc = 0.f; c = 0.f; curg = g;
        }
        acc += h[i * ND + lane];
        c += 1.f;
    }
    atomicAdd(&pooled[curg * ND + lane], acc);
    if (lane == 0) atomicAdd(&cnt[curg], c);
}

__global__ __launch_bounds__(256) void k_readout(
    const float* __restrict__ pooled, const float* __restrict__ cnt,
    const float* __restrict__ Wo1, const float* __restrict__ bo1,
    const float* __restrict__ Wo2, const float* __restrict__ bo2,
    float* __restrict__ out) {
    __shared__ float pbuf[WPB][ND];
    int lane = threadIdx.x & 63;
    int wid = threadIdx.x >> 6;
    int g = blockIdx.x * WPB + wid;
    bool valid = g < N_GRAPH;
    int gc = valid ? g : N_GRAPH - 1;
    float c = fmaxf(cnt[gc], 1.f);
    pbuf[wid][lane] = pooled[gc * ND + lane] / c;
    __syncthreads();
    float h0 = bo1[lane], h1 = bo1[64 + lane];
#pragma unroll 8
    for (int k = 0; k < ND; ++k) {
        float pk = pbuf[wid][k];
        h0 += pk * Wo1[k * HD + lane];
        h1 += pk * Wo1[k * HD + 64 + lane];
    }
    float s = sp(h0) * Wo2[lane] + sp(h1) * Wo2[64 + lane];
#pragma unroll
    for (int off = 32; off; off >>= 1) s += __shfl_down(s, off);
    if (valid && lane == 0) out[g] = s + bo2[0];
}

extern "C" void kernel_launch(void* const* d_in, const int* in_sizes, int n_in,
                              void* d_out, int out_size, void* d_ws, size_t ws_size,
                              hipStream_t stream) {
    const float* x       = (const float*)d_in[0];
    const float* ea      = (const float*)d_in[1];
    const int*   ei      = (const int*)d_in[2];
    const int*   batch   = (const int*)d_in[3];
    const float* Wnp     = (const float*)d_in[4];
    const float* bnp     = (const float*)d_in[5];
    const float* g_np    = (const float*)d_in[6];
    const float* be_np   = (const float*)d_in[7];
    const float* Wep     = (const float*)d_in[8];
    const float* bep     = (const float*)d_in[9];
    const float* We1     = (const float*)d_in[10];
    const float* be1     = (const float*)d_in[11];
    const float* We2     = (const float*)d_in[12];
    const float* be2     = (const float*)d_in[13];
    const float* Wn1     = (const float*)d_in[14];
    const float* bn1     = (const float*)d_in[15];
    const float* Wn2     = (const float*)d_in[16];
    const float* bn2     = (const float*)d_in[17];
    const float* g_bn    = (const float*)d_in[18];
    const float* b_bn    = (const float*)d_in[19];
    const float* Wo1     = (const float*)d_in[20];
    const float* bo1     = (const float*)d_in[21];
    const float* Wo2     = (const float*)d_in[22];
    const float* bo2     = (const float*)d_in[23];

    float* ws = (float*)d_ws;
    size_t off = 0;
    float* h      = ws + off; off += (size_t)N_NODES * ND;
    float* t      = ws + off; off += (size_t)N_NODES * ND;
    float* aggr   = ws + off; off += (size_t)N_NODES * HD;
    float* stats  = ws + off; off += 2 * ND;
    float* ss     = ws + off; off += 2 * ND;
    float* pooled = ws + off; off += N_GRAPH * ND;
    float* cnt    = ws + off; off += 512;
    unsigned short* h_bf = (unsigned short*)(ws + off); off += (size_t)N_NODES * ND / 2;
    unsigned short* pA1  = (unsigned short*)(ws + off); off += 5 * 8 * 64 * 8 / 2;
    unsigned short* pA2  = (unsigned short*)(ws + off); off += 4 * 8 * 64 * 8 / 2;
    int* sS       = (int*)(ws + off); off += N_EDGES;
    int* sE       = (int*)(ws + off); off += N_EDGES;
    int* hist     = (int*)(ws + off); off += N_NODES;
    int* cursor   = (int*)(ws + off); off += N_NODES;
    int* rowptr   = (int*)(ws + off); off += N_NODES;
    int* chunksum = (int*)(ws + off); off += 64;
    size_t base_bytes = off * sizeof(float);
    unsigned short* e_bf = (unsigned short*)(ws + off);
    bool epre = (ws_size >= base_bytes + (size_t)N_EDGES * 32 * 2);

    float* outp = (float*)d_out;

    const int NCH = (N_NODES + 1023) / 1024;  // 49

    // ---- counting sort of edges by dst -> CSR (once per call) ----
    hipMemsetAsync(hist, 0, N_NODES * sizeof(int), stream);
    k_hist<<<(N_EDGES + 255) / 256, 256, 0, stream>>>(ei, hist);
    k_scan1<<<NCH, 1024, 0, stream>>>(hist, chunksum);
    k_scan2<<<1, 64, 0, stream>>>(chunksum, NCH);
    k_scan3<<<NCH, 1024, 0, stream>>>(hist, chunksum, cursor, rowptr);
    k_scatter<<<(N_EDGES + 255) / 256, 256, 0, stream>>>(ei, cursor, sS, sE);
    if (epre)
        k_eproj_sorted<<<(int)(((long)N_EDGES * 32 + 255) / 256), 256, 0, stream>>>(
            ea, sE, Wep, bep, e_bf);

    // ---- node projection + BN ----
    hipMemsetAsync(stats, 0, 2 * ND * sizeof(float), stream);
    k_node_proj<<<512, 256, 0, stream>>>(x, Wnp, bnp, t, stats);
    k_bn_finalize<<<1, 64, 0, stream>>>(stats, g_np, be_np, ss);
    k_bn_apply<<<2048, 256, 0, stream>>>(t, ss, h, h_bf);

    for (int l = 0; l < 3; ++l) {
        k_pack_w<<<(5 * 8 * 64 + 255) / 256, 256, 0, stream>>>(
            We1 + (size_t)l * 160 * HD, pA1, 5);
        k_pack_w<<<(4 * 8 * 64 + 255) / 256, 256, 0, stream>>>(
            We2 + (size_t)l * HD * HD, pA2, 4);

        if (epre)
            k_edge_node<true><<<(N_NODES + WPB - 1) / WPB, 256, 0, stream>>>(
                h_bf, e_bf, ea, sE, Wep, bep, rowptr, hist, sS,
                pA1, be1 + l * HD, pA2, be2 + l * HD, aggr);
        else
            k_edge_node<false><<<(N_NODES + WPB - 1) / WPB, 256, 0, stream>>>(
                h_bf, e_bf, ea, sE, Wep, bep, rowptr, hist, sS,
                pA1, be1 + l * HD, pA2, be2 + l * HD, aggr);

        hipMemsetAsync(stats, 0, 2 * ND * sizeof(float), stream);
        k_node_update<<<512, 256, 0, stream>>>(
            h, aggr,
            Wn1 + (size_t)l * (ND + HD) * HD, bn1 + l * HD,
            Wn2 + (size_t)l * HD * ND, bn2 + l * ND, t, stats);
        k_bn_finalize<<<1, 64, 0, stream>>>(stats, g_bn + l * ND, b_bn + l * ND, ss);
        k_bn_apply<<<2048, 256, 0, stream>>>(t, ss, h, h_bf);
    }

    hipMemsetAsync(pooled, 0, (size_t)(N_GRAPH * ND + 512) * sizeof(float), stream);
    k_pool<<<512, 256, 0, stream>>>(h, batch, pooled, cnt);
    k_readout<<<(N_GRAPH + WPB - 1) / WPB, 256, 0, stream>>>(
        pooled, cnt, Wo1, bo1, Wo2, bo2, outp);
}

// Round 9
// 4633.931 us; speedup vs baseline: 1.8689x; 1.0286x over previous
//
#include <hip/hip_runtime.h>
#include <hip/hip_bf16.h>

#define N_NODES 50000
#define N_EDGES 800000
#define N_GRAPH 500
#define ND 64
#define ED 32
#define HD 128
#define WPB 4   // waves per block (256 threads)

typedef __attribute__((ext_vector_type(8))) short bf16x8;
typedef __attribute__((ext_vector_type(4))) float f32x4;

__device__ __forceinline__ float sp(float x) {
    return fmaxf(x, 0.f) + log1pf(expf(-fabsf(x)));
}

// fast softplus for the bf16 edge path (v_exp_f32/v_log_f32 based)
__device__ __forceinline__ float spf(float x) {
    return fmaxf(x, 0.f) + __logf(1.f + __expf(-fabsf(x)));
}

__device__ __forceinline__ unsigned short f2bf(float v) {
    __hip_bfloat16 b = __float2bfloat16(v);
    return *(unsigned short*)&b;
}

__device__ __forceinline__ unsigned int pkbf(float a, float b) {
    return (unsigned int)f2bf(a) | ((unsigned int)f2bf(b) << 16);
}

// ---------------- node projection + BN (fp32) ---------------------------
__global__ __launch_bounds__(256) void k_node_proj(
    const float* __restrict__ x, const float* __restrict__ Wnp,
    const float* __restrict__ bnp, float* __restrict__ t,
    float* __restrict__ stats) {
    int lane = threadIdx.x & 63;
    int wave = (blockIdx.x * blockDim.x + threadIdx.x) >> 6;
    int nw = (gridDim.x * blockDim.x) >> 6;
    float w[13];
#pragma unroll
    for (int k = 0; k < 13; ++k) w[k] = Wnp[k * ND + lane];
    float bb = bnp[lane];
    float s0 = 0.f, s1 = 0.f;
    for (int i = wave; i < N_NODES; i += nw) {
        float acc = bb;
#pragma unroll
        for (int k = 0; k < 13; ++k) acc += x[i * 13 + k] * w[k];
        float v = sp(acc);
        t[i * ND + lane] = v;
        s0 += v; s1 += v * v;
    }
    atomicAdd(&stats[lane], s0);
    atomicAdd(&stats[ND + lane], s1);
}

__global__ void k_bn_finalize(const float* __restrict__ stats,
                              const float* __restrict__ g,
                              const float* __restrict__ b,
                              float* __restrict__ ss) {
    int j = threadIdx.x;
    if (j >= ND) return;
    float inv_n = 1.f / (float)N_NODES;
    float mu = stats[j] * inv_n;
    float var = stats[ND + j] * inv_n - mu * mu;
    float rs = rsqrtf(var + 1e-5f);
    float sc = rs * g[j];
    ss[j] = sc;
    ss[ND + j] = b[j] - mu * sc;
}

__global__ __launch_bounds__(256) void k_bn_apply(
    const float* __restrict__ t, const float* __restrict__ ss,
    float* __restrict__ h, unsigned short* __restrict__ hb) {
    int idx = blockIdx.x * blockDim.x + threadIdx.x;
    int tot = N_NODES * ND;
    int stride = gridDim.x * blockDim.x;
    for (; idx < tot; idx += stride) {
        int c = idx & (ND - 1);
        float v = t[idx] * ss[c] + ss[ND + c];
        h[idx] = v;
        hb[idx] = f2bf(v);
    }
}

// ---------------- counting sort of edges by dst -------------------------
__global__ __launch_bounds__(256) void k_hist(const int* __restrict__ ei,
                                              int* __restrict__ hist) {
    int e = blockIdx.x * 256 + threadIdx.x;
    if (e < N_EDGES) atomicAdd(&hist[ei[N_EDGES + e]], 1);
}

__global__ __launch_bounds__(1024) void k_scan1(const int* __restrict__ hist,
                                                int* __restrict__ chunksum) {
    __shared__ int s[1024];
    int t = threadIdx.x;
    int i = blockIdx.x * 1024 + t;
    s[t] = (i < N_NODES) ? hist[i] : 0;
    __syncthreads();
    for (int off = 512; off; off >>= 1) {
        if (t < off) s[t] += s[t + off];
        __syncthreads();
    }
    if (t == 0) chunksum[blockIdx.x] = s[0];
}

__global__ void k_scan2(int* __restrict__ chunksum, int n) {
    if (threadIdx.x == 0) {
        int acc = 0;
        for (int i = 0; i < n; ++i) { int v = chunksum[i]; chunksum[i] = acc; acc += v; }
    }
}

__global__ __launch_bounds__(1024) void k_scan3(const int* __restrict__ hist,
                                                const int* __restrict__ chunksum,
                                                int* __restrict__ cursor,
                                                int* __restrict__ rowptr) {
    __shared__ int s[1024];
    int t = threadIdx.x;
    int i = blockIdx.x * 1024 + t;
    int v = (i < N_NODES) ? hist[i] : 0;
    s[t] = v;
    __syncthreads();
    for (int off = 1; off < 1024; off <<= 1) {
        int u = (t >= off) ? s[t - off] : 0;
        __syncthreads();
        s[t] += u;
        __syncthreads();
    }
    if (i < N_NODES) {
        int ex = chunksum[blockIdx.x] + s[t] - v;  // exclusive scan
        cursor[i] = ex;
        rowptr[i] = ex;
    }
}

__global__ __launch_bounds__(256) void k_scatter(const int* __restrict__ ei,
                                                 int* __restrict__ cursor,
                                                 int* __restrict__ sS,
                                                 int* __restrict__ sE) {
    int e = blockIdx.x * 256 + threadIdx.x;
    if (e >= N_EDGES) return;
    int d = ei[N_EDGES + e];
    int pos = atomicAdd(&cursor[d], 1);
    sS[pos] = ei[e];
    sE[pos] = e;
}

// edge projection into sorted order (layer-invariant, once per call)
__global__ __launch_bounds__(256) void k_eproj_sorted(
    const float* __restrict__ ea, const int* __restrict__ sE,
    const float* __restrict__ Wep, const float* __restrict__ bep,
    unsigned short* __restrict__ e_bf) {
    long idx = (long)blockIdx.x * blockDim.x + threadIdx.x;
    long tot = (long)N_EDGES * 32;
    if (idx >= tot) return;
    int p = (int)(idx >> 5), col = (int)(idx & 31);
    int e = sE[p];
    float v = spf(ea[2 * e] * Wep[col] + ea[2 * e + 1] * Wep[32 + col] + bep[col]);
    e_bf[idx] = f2bf(v);
}

// ---------------- weight pack: W[K][128] -> A-frag layout ---------------
__global__ __launch_bounds__(256) void k_pack_w(
    const float* __restrict__ W, unsigned short* __restrict__ out, int ksteps) {
    int tid = blockIdx.x * blockDim.x + threadIdx.x;
    int total = ksteps * 8 * 64;
    if (tid >= total) return;
    int l = tid & 63; int fr = tid >> 6; int nf = fr & 7; int ks = fr >> 3;
    int n = 16 * nf + (l & 15);
    int k0 = 32 * ks + 8 * (l >> 4);
#pragma unroll
    for (int r = 0; r < 8; ++r)
        out[tid * 8 + r] = f2bf(W[(k0 + r) * 128 + n]);
}

// ---------------- node-centric MFMA edge conv (CSR, no atomics) ---------
// One wave per node. Register-pressure-bounded structure: B fragments
// loaded once per tile (20 regs), each GEMM's N-dim split into two halves
// of 4 fragments so at most ~20 A-loads are hoistable per region. This
// keeps worst-case live set < 256 regs -> no scratch spill (rounds 7/8
// regression: full-unroll exposed 40 A-loads -> compiler spilled ~4.5 GB).
template <bool EPRE>
__global__ __launch_bounds__(256, 2) void k_edge_node(
    const unsigned short* __restrict__ h_bf, const unsigned short* __restrict__ e_bf,
    const float* __restrict__ ea, const int* __restrict__ sE,
    const float* __restrict__ Wep, const float* __restrict__ bep,
    const int* __restrict__ rowptr, const int* __restrict__ hist,
    const int* __restrict__ sS,
    const unsigned short* __restrict__ pA1, const float* __restrict__ be1,
    const unsigned short* __restrict__ pA2, const float* __restrict__ be2,
    float* __restrict__ aggr) {
    __shared__ unsigned short P[WPB][16][136];

    int lane = threadIdx.x & 63;
    int w = threadIdx.x >> 6;
    int m = lane & 15, g = lane >> 4;
    int node = blockIdx.x * WPB + w;
    if (node >= N_NODES) return;
    int start = rowptr[node];
    int deg = hist[node];

    float rs[8][4];
#pragma unroll
    for (int nf = 0; nf < 8; ++nf)
#pragma unroll
        for (int j = 0; j < 4; ++j) rs[nf][j] = 0.f;

    int nt = (deg + 15) >> 4;
    for (int t = 0; t < nt; ++t) {
        int rem = deg - (t << 4);           // > 0
        int me = min(m, rem - 1);           // clamped edge slot
        int p = start + (t << 4) + me;      // sorted edge position
        int src = sS[p];
        bool valid = (m < rem);

        // ---- load the 5 B fragments (z-row: dst 64 | src 64 | e 32) ----
        bf16x8 bfr[5];
        bfr[0] = *(const bf16x8*)(h_bf + (size_t)node * 64 + 8 * g);
        bfr[1] = *(const bf16x8*)(h_bf + (size_t)node * 64 + 32 + 8 * g);
        bfr[2] = *(const bf16x8*)(h_bf + (size_t)src * 64 + 8 * g);
        bfr[3] = *(const bf16x8*)(h_bf + (size_t)src * 64 + 32 + 8 * g);
        if constexpr (EPRE) {
            bfr[4] = *(const bf16x8*)(e_bf + (size_t)p * 32 + 8 * g);
        } else {
            int eo = sE[p];
            float a0 = ea[2 * eo], a1 = ea[2 * eo + 1];
            bf16x8 bt;
#pragma unroll
            for (int r = 0; r < 8; ++r) {
                int col = 8 * g + r;
                bt[r] = (short)f2bf(spf(a0 * Wep[col] + a1 * Wep[32 + col] + bep[col]));
            }
            bfr[4] = bt;
        }

        // ---- GEMM1 in two nf-halves (bounds register live-set) ----
#pragma unroll
        for (int half = 0; half < 2; ++half) {
            f32x4 acc[4];
#pragma unroll
            for (int n2 = 0; n2 < 4; ++n2) acc[n2] = (f32x4){0.f, 0.f, 0.f, 0.f};
#pragma unroll
            for (int ks = 0; ks < 5; ++ks) {
#pragma unroll
                for (int n2 = 0; n2 < 4; ++n2) {
                    int nf = half * 4 + n2;
                    bf16x8 a = *(const bf16x8*)(pA1 + ((ks * 8 + nf) * 64 + lane) * 8);
                    acc[n2] = __builtin_amdgcn_mfma_f32_16x16x32_bf16(a, bfr[ks], acc[n2], 0, 0, 0);
                }
            }
            // epilogue 1 (this half): bias + softplus -> P (bf16)
#pragma unroll
            for (int n2 = 0; n2 < 4; ++n2) {
                int nf = half * 4 + n2;
                f32x4 bb = *(const f32x4*)(be1 + 16 * nf + 4 * g);
                f32x4 c = acc[n2];
                unsigned int u01 = pkbf(spf(c[0] + bb[0]), spf(c[1] + bb[1]));
                unsigned int u23 = pkbf(spf(c[2] + bb[2]), spf(c[3] + bb[3]));
                unsigned int* dst = (unsigned int*)&P[w][m][16 * nf + 4 * g];
                dst[0] = u01; dst[1] = u23;
            }
        }

        // ---- GEMM2: B = P^T rows from LDS (wave-private) ----
        bf16x8 pfr[4];
#pragma unroll
        for (int ks = 0; ks < 4; ++ks)
            pfr[ks] = *(const bf16x8*)&P[w][m][32 * ks + 8 * g];

#pragma unroll
        for (int half = 0; half < 2; ++half) {
            f32x4 acc2[4];
#pragma unroll
            for (int n2 = 0; n2 < 4; ++n2) acc2[n2] = (f32x4){0.f, 0.f, 0.f, 0.f};
#pragma unroll
            for (int ks = 0; ks < 4; ++ks) {
#pragma unroll
                for (int n2 = 0; n2 < 4; ++n2) {
                    int nf = half * 4 + n2;
                    bf16x8 a = *(const bf16x8*)(pA2 + ((ks * 8 + nf) * 64 + lane) * 8);
                    acc2[n2] = __builtin_amdgcn_mfma_f32_16x16x32_bf16(a, pfr[ks], acc2[n2], 0, 0, 0);
                }
            }
            // epilogue 2 (this half): bias + softplus, masked accumulate
#pragma unroll
            for (int n2 = 0; n2 < 4; ++n2) {
                int nf = half * 4 + n2;
                f32x4 bb = *(const f32x4*)(be2 + 16 * nf + 4 * g);
                f32x4 c = acc2[n2];
#pragma unroll
                for (int j = 0; j < 4; ++j) {
                    float v = spf(c[j] + bb[j]);
                    rs[nf][j] += valid ? v : 0.f;
                }
            }
        }
    }

    // ---- reduce over the 16-edge (m) dimension, store once ----
#pragma unroll
    for (int nf = 0; nf < 8; ++nf)
#pragma unroll
        for (int j = 0; j < 4; ++j) {
            float v = rs[nf][j];
            v += __shfl_xor(v, 1);
            v += __shfl_xor(v, 2);
            v += __shfl_xor(v, 4);
            v += __shfl_xor(v, 8);
            rs[nf][j] = v;
        }
    if (m == 0) {
        float* base = aggr + (size_t)node * HD;
#pragma unroll
        for (int nf = 0; nf < 8; ++nf) {
            f32x4 v = { rs[nf][0], rs[nf][1], rs[nf][2], rs[nf][3] };
            *(f32x4*)(base + 16 * nf + 4 * g) = v;
        }
    }
}

// ---------------- node update (fp32, unchanged) -------------------------
__global__ __launch_bounds__(256) void k_node_update(
    const float* __restrict__ h, const float* __restrict__ aggr,
    const float* __restrict__ Wn1, const float* __restrict__ bn1,
    const float* __restrict__ Wn2, const float* __restrict__ bn2,
    float* __restrict__ t, float* __restrict__ stats) {
    __shared__ float zb[WPB][ND + HD];
    __shared__ float pb[WPB][HD];
    int lane = threadIdx.x & 63;
    int wid = threadIdx.x >> 6;
    int wave = (blockIdx.x * blockDim.x + threadIdx.x) >> 6;
    int nw = (gridDim.x * blockDim.x) >> 6;
    int iters = (N_NODES + nw - 1) / nw;
    float s0 = 0.f, s1 = 0.f;
    for (int it = 0; it < iters; ++it) {
        int i = wave + it * nw;
        bool valid = i < N_NODES;
        int ic = valid ? i : N_NODES - 1;
        float hv = h[ic * ND + lane];
        zb[wid][lane] = hv;
        zb[wid][ND + lane] = aggr[ic * HD + lane];
        zb[wid][ND + 64 + lane] = aggr[ic * HD + 64 + lane];
        __syncthreads();
        float h0 = bn1[lane], h1 = bn1[64 + lane];
#pragma unroll 8
        for (int k = 0; k < ND + HD; ++k) {
            float zk = zb[wid][k];
            h0 += zk * Wn1[k * HD + lane];
            h1 += zk * Wn1[k * HD + 64 + lane];
        }
        pb[wid][lane] = sp(h0);
        pb[wid][64 + lane] = sp(h1);
        __syncthreads();
        float o = bn2[lane];
#pragma unroll 8
        for (int k = 0; k < HD; ++k) o += pb[wid][k] * Wn2[k * ND + lane];
        if (valid) {
            float tn = o + hv;
            t[ic * ND + lane] = tn;
            s0 += tn; s1 += tn * tn;
        }
        __syncthreads();
    }
    atomicAdd(&stats[lane], s0);
    atomicAdd(&stats[ND + lane], s1);
}

// ---------------- pooling + readout (unchanged) -------------------------
__global__ __launch_bounds__(256) void k_pool(
    const float* __restrict__ h, const int* __restrict__ batch,
    float* __restrict__ pooled, float* __restrict__ cnt) {
    int lane = threadIdx.x & 63;
    int wave = (blockIdx.x * blockDim.x + threadIdx.x) >> 6;
    int nw = (gridDim.x * blockDim.x) >> 6;
    int chunk = (N_NODES + nw - 1) / nw;
    int s = wave * chunk;
    int epos = min(N_NODES, s + chunk);
    if (s >= N_NODES) return;
    int curg = batch[s];
    float acc = 0.f, c = 0.f;
    for (int i = s; i < epos; ++i) {
        int g = batch[i];
        if (g != curg) {
            atomicAdd(&pooled[curg * ND + lane], acc);
            if (lane == 0) atomicAdd(&cnt[curg], c);
            acc = 0.f; c = 0.f; curg = g;
        }
        acc += h[i * ND + lane];
        c += 1.f;
    }
    atomicAdd(&pooled[curg * ND + lane], acc);
    if (lane == 0) atomicAdd(&cnt[curg], c);
}

__global__ __launch_bounds__(256) void k_readout(
    const float* __restrict__ pooled, const float* __restrict__ cnt,
    const float* __restrict__ Wo1, const float* __restrict__ bo1,
    const float* __restrict__ Wo2, const float* __restrict__ bo2,
    float* __restrict__ out) {
    __shared__ float pbuf[WPB][ND];
    int lane = threadIdx.x & 63;
    int wid = threadIdx.x >> 6;
    int g = blockIdx.x * WPB + wid;
    bool valid = g < N_GRAPH;
    int gc = valid ? g : N_GRAPH - 1;
    float c = fmaxf(cnt[gc], 1.f);
    pbuf[wid][lane] = pooled[gc * ND + lane] / c;
    __syncthreads();
    float h0 = bo1[lane], h1 = bo1[64 + lane];
#pragma unroll 8
    for (int k = 0; k < ND; ++k) {
        float pk = pbuf[wid][k];
        h0 += pk * Wo1[k * HD + lane];
        h1 += pk * Wo1[k * HD + 64 + lane];
    }
    float s = sp(h0) * Wo2[lane] + sp(h1) * Wo2[64 + lane];
#pragma unroll
    for (int off = 32; off; off >>= 1) s += __shfl_down(s, off);
    if (valid && lane == 0) out[g] = s + bo2[0];
}

extern "C" void kernel_launch(void* const* d_in, const int* in_sizes, int n_in,
                              void* d_out, int out_size, void* d_ws, size_t ws_size,
                              hipStream_t stream) {
    const float* x       = (const float*)d_in[0];
    const float* ea      = (const float*)d_in[1];
    const int*   ei      = (const int*)d_in[2];
    const int*   batch   = (const int*)d_in[3];
    const float* Wnp     = (const float*)d_in[4];
    const float* bnp     = (const float*)d_in[5];
    const float* g_np    = (const float*)d_in[6];
    const float* be_np   = (const float*)d_in[7];
    const float* Wep     = (const float*)d_in[8];
    const float* bep     = (const float*)d_in[9];
    const float* We1     = (const float*)d_in[10];
    const float* be1     = (const float*)d_in[11];
    const float* We2     = (const float*)d_in[12];
    const float* be2     = (const float*)d_in[13];
    const float* Wn1     = (const float*)d_in[14];
    const float* bn1     = (const float*)d_in[15];
    const float* Wn2     = (const float*)d_in[16];
    const float* bn2     = (const float*)d_in[17];
    const float* g_bn    = (const float*)d_in[18];
    const float* b_bn    = (const float*)d_in[19];
    const float* Wo1     = (const float*)d_in[20];
    const float* bo1     = (const float*)d_in[21];
    const float* Wo2     = (const float*)d_in[22];
    const float* bo2     = (const float*)d_in[23];

    float* ws = (float*)d_ws;
    size_t off = 0;
    float* h      = ws + off; off += (size_t)N_NODES * ND;
    float* t      = ws + off; off += (size_t)N_NODES * ND;
    float* aggr   = ws + off; off += (size_t)N_NODES * HD;
    float* stats  = ws + off; off += 2 * ND;
    float* ss     = ws + off; off += 2 * ND;
    float* pooled = ws + off; off += N_GRAPH * ND;
    float* cnt    = ws + off; off += 512;
    unsigned short* h_bf = (unsigned short*)(ws + off); off += (size_t)N_NODES * ND / 2;
    unsigned short* pA1  = (unsigned short*)(ws + off); off += 5 * 8 * 64 * 8 / 2;
    unsigned short* pA2  = (unsigned short*)(ws + off); off += 4 * 8 * 64 * 8 / 2;
    int* sS       = (int*)(ws + off); off += N_EDGES;
    int* sE       = (int*)(ws + off); off += N_EDGES;
    int* hist     = (int*)(ws + off); off += N_NODES;
    int* cursor   = (int*)(ws + off); off += N_NODES;
    int* rowptr   = (int*)(ws + off); off += N_NODES;
    int* chunksum = (int*)(ws + off); off += 64;
    size_t base_bytes = off * sizeof(float);
    unsigned short* e_bf = (unsigned short*)(ws + off);
    bool epre = (ws_size >= base_bytes + (size_t)N_EDGES * 32 * 2);

    float* outp = (float*)d_out;

    const int NCH = (N_NODES + 1023) / 1024;  // 49

    // ---- counting sort of edges by dst -> CSR (once per call) ----
    hipMemsetAsync(hist, 0, N_NODES * sizeof(int), stream);
    k_hist<<<(N_EDGES + 255) / 256, 256, 0, stream>>>(ei, hist);
    k_scan1<<<NCH, 1024, 0, stream>>>(hist, chunksum);
    k_scan2<<<1, 64, 0, stream>>>(chunksum, NCH);
    k_scan3<<<NCH, 1024, 0, stream>>>(hist, chunksum, cursor, rowptr);
    k_scatter<<<(N_EDGES + 255) / 256, 256, 0, stream>>>(ei, cursor, sS, sE);
    if (epre)
        k_eproj_sorted<<<(int)(((long)N_EDGES * 32 + 255) / 256), 256, 0, stream>>>(
            ea, sE, Wep, bep, e_bf);

    // ---- node projection + BN ----
    hipMemsetAsync(stats, 0, 2 * ND * sizeof(float), stream);
    k_node_proj<<<512, 256, 0, stream>>>(x, Wnp, bnp, t, stats);
    k_bn_finalize<<<1, 64, 0, stream>>>(stats, g_np, be_np, ss);
    k_bn_apply<<<2048, 256, 0, stream>>>(t, ss, h, h_bf);

    for (int l = 0; l < 3; ++l) {
        k_pack_w<<<(5 * 8 * 64 + 255) / 256, 256, 0, stream>>>(
            We1 + (size_t)l * 160 * HD, pA1, 5);
        k_pack_w<<<(4 * 8 * 64 + 255) / 256, 256, 0, stream>>>(
            We2 + (size_t)l * HD * HD, pA2, 4);

        if (epre)
            k_edge_node<true><<<(N_NODES + WPB - 1) / WPB, 256, 0, stream>>>(
                h_bf, e_bf, ea, sE, Wep, bep, rowptr, hist, sS,
                pA1, be1 + l * HD, pA2, be2 + l * HD, aggr);
        else
            k_edge_node<false><<<(N_NODES + WPB - 1) / WPB, 256, 0, stream>>>(
                h_bf, e_bf, ea, sE, Wep, bep, rowptr, hist, sS,
                pA1, be1 + l * HD, pA2, be2 + l * HD, aggr);

        hipMemsetAsync(stats, 0, 2 * ND * sizeof(float), stream);
        k_node_update<<<512, 256, 0, stream>>>(
            h, aggr,
            Wn1 + (size_t)l * (ND + HD) * HD, bn1 + l * HD,
            Wn2 + (size_t)l * HD * ND, bn2 + l * ND, t, stats);
        k_bn_finalize<<<1, 64, 0, stream>>>(stats, g_bn + l * ND, b_bn + l * ND, ss);
        k_bn_apply<<<2048, 256, 0, stream>>>(t, ss, h, h_bf);
    }

    hipMemsetAsync(pooled, 0, (size_t)(N_GRAPH * ND + 512) * sizeof(float), stream);
    k_pool<<<512, 256, 0, stream>>>(h, batch, pooled, cnt);
    k_readout<<<(N_GRAPH + WPB - 1) / WPB, 256, 0, stream>>>(
        pooled, cnt, Wo1, bo1, Wo2, bo2, outp);
}